// Round 5
// baseline (459.068 us; speedup 1.0000x reference)
//
#include <hip/hip_runtime.h>
#include <stdint.h>

#define BB 32
#define NN 2048
#define HH 128
#define BN (BB*NN)

typedef short v8s __attribute__((ext_vector_type(8)));
typedef float v4f __attribute__((ext_vector_type(4)));

__device__ __forceinline__ unsigned short f2b(float f){
  union { float f; unsigned int i; } v; v.f = f;
  unsigned int x = v.i;
  unsigned int r = x + 0x7FFFu + ((x >> 16) & 1u);   // RNE f32 -> bf16
  return (unsigned short)(r >> 16);
}
__device__ __forceinline__ unsigned int pk2(float a, float b){
  return (unsigned int)f2b(a) | ((unsigned int)f2b(b) << 16);
}
__device__ __forceinline__ float frcp(float x){ return __builtin_amdgcn_rcpf(x); }
// fast sigmoid / tanh: v_exp + v_rcp, ~1e-6 rel err (<< bf16 gate noise)
__device__ __forceinline__ float fsigm(float x){ return frcp(1.0f + __expf(-x)); }
__device__ __forceinline__ float ftanh(float x){ return 1.0f - 2.0f*frcp(1.0f + __expf(2.0f*x)); }

// ---------------- pre-swizzle B = [Wi;Wh] (f32) into bf16 MFMA fragment order
// Bsw[((kc*32+ct)*64 + lane)*8 + j] = bf16(Bcat[kc*32 + (lane>>4)*8 + j][ct*16 + (lane&15)])
__global__ void kswz(const float* __restrict__ Wi0, const float* __restrict__ Wh0,
                     const float* __restrict__ Wi1, const float* __restrict__ Wh1,
                     unsigned short* __restrict__ Bsw0, unsigned short* __restrict__ Bsw1){
  int bid = blockIdx.x;            // 0..511
  int layer = bid >> 8;
  int kc = (bid >> 5) & 7;
  int ct = bid & 31;
  int lane = threadIdx.x;          // 0..63
  const float* Wi = layer ? Wi1 : Wi0;
  const float* Wh = layer ? Wh1 : Wh0;
  unsigned short* dst = layer ? Bsw1 : Bsw0;
  int col = ct*16 + (lane & 15);
  int kbase = kc*32 + (lane >> 4)*8;
  size_t o = ((size_t)(kc*32 + ct)*64 + (size_t)lane)*8;
  #pragma unroll
  for (int j = 0; j < 8; j++){
    int k = kbase + j;
    dst[o + j] = f2b((k < 128) ? Wi[k*512 + col] : Wh[(k-128)*512 + col]);
  }
}

// ---------------- fused 2-layer LSTM + decision head ------------------------
// Block: 32 rows, 512 threads (8 waves). Wave w owns channels w*16..w*16+15 of
// every gate. A tiles staged in LDS as bf16; h0_new -> separate LDS (ldsG).
// Decision head is SPLIT: layer-0 contribution reduced in epilogue 0 -> ldsR
// slot 0; layer-1 contribution in epilogue 1 -> slot 1; finisher sums both.
// Nothing from the decision head stays in registers across GEMM1 (spill fix).
// Global c/h stores are PREDICATED OFF at exit/raise NODE rows (replaces
// ksave/krestore). wbuf for those rows is fixed later by kpatch.
#define ROWSB 32
#define PA 264   // ushorts/row of A tile: 256 + 8 pad
#define PH 136   // ushorts/row of H tiles: 128 + 8 pad

__global__ __launch_bounds__(512, 4) void klstm2(
    const float* __restrict__ ne,
    float* __restrict__ c0, float* __restrict__ h0,
    float* __restrict__ c1, float* __restrict__ h1,
    const unsigned short* __restrict__ Bsw0, const float* __restrict__ b0,
    const unsigned short* __restrict__ Bsw1, const float* __restrict__ b1,
    const float* __restrict__ Wr, const float* __restrict__ br,
    const float* __restrict__ Wb, const float* __restrict__ bb,
    const float* __restrict__ ip,
    const int* __restrict__ exit_idx, const int* __restrict__ raise_idx,
    const int* __restrict__ ri, const int* __restrict__ ti, const int* __restrict__ fi,
    int* __restrict__ counts,
    float* __restrict__ wbuf,
    const int* __restrict__ step_limits, const int* __restrict__ cur_step)
{
  __shared__ unsigned short ldsA[ROWSB*PA];   // [ne | h0_old] bf16
  __shared__ unsigned short ldsH[ROWSB*PH];   // h1_old bf16
  __shared__ unsigned short ldsG[ROWSB*PH];   // h0_new bf16
  __shared__ float ldsR[2][ROWSB*8*4];        // decision partials [slot][row][wid][4]

  int rowbase = blockIdx.x * ROWSB;           // 32 rows, never crosses a batch
  int b = rowbase >> 11;
  if (cur_step[0] >= step_limits[b]) return;  // done batch: keep old states

  int tid = threadIdx.x;
  int wid = tid >> 6, lane = tid & 63;
  int quad = lane >> 4, l16 = lane & 15;
  int ch = wid*16 + l16;            // channel within each gate (0..127)
  int e_row = exit_idx[b], r_row = raise_idx[b];   // NODE indices (0..2047)

  // ---- stage A0 = bf16([ne | h0_old]) : 4 float4 per thread ----
  #pragma unroll
  for (int p = 0; p < 4; p++){
    int idx = p*512 + tid;
    int row = idx >> 6, chunk = idx & 63;     // chunk = float4 index (0..63)
    size_t g = (size_t)(rowbase + row)*128 + (chunk & 31)*4;
    float4 v = (chunk < 32) ? *(const float4*)(ne + g) : *(const float4*)(h0 + g);
    uint2 w; w.x = pk2(v.x, v.y); w.y = pk2(v.z, v.w);
    *(uint2*)&ldsA[row*PA + chunk*4] = w;
  }
  // ---- stage H1 = bf16(h1_old) (consumed only after second barrier) ----
  #pragma unroll
  for (int p = 0; p < 2; p++){
    int idx = p*512 + tid;
    int row = idx >> 5, chunk = idx & 31;
    float4 v = *(const float4*)(h1 + (size_t)(rowbase + row)*128 + chunk*4);
    uint2 w; w.x = pk2(v.x, v.y); w.y = pk2(v.z, v.w);
    *(uint2*)&ldsH[row*PH + chunk*4] = w;
  }

  // ---- prefetch c0 rows + biases + first B frags (independent of LDS) ----
  float cpre[8], bias[4];
  #pragma unroll
  for (int rt = 0; rt < 2; rt++)
    #pragma unroll
    for (int r = 0; r < 4; r++)
      cpre[rt*4+r] = c0[((size_t)rowbase + rt*16 + quad*4 + r)*128 + ch];
  #pragma unroll
  for (int g = 0; g < 4; g++) bias[g] = b0[g*128 + ch];
  const v8s* Bv0 = (const v8s*)Bsw0;
  v8s bc[4], bn[4];
  #pragma unroll
  for (int g = 0; g < 4; g++) bc[g] = Bv0[(size_t)(g*8 + wid)*64 + lane];

  __syncthreads();

  // ================= layer 0: gates = [ne|h0_old] @ B0 =================
  v4f acc[2][4] = {};
  #pragma unroll
  for (int kc = 0; kc < 8; kc++){
    if (kc < 7){
      #pragma unroll
      for (int g = 0; g < 4; g++) bn[g] = Bv0[(size_t)((kc+1)*32 + g*8 + wid)*64 + lane];
    }
    v8s a0 = *(const v8s*)&ldsA[(0*16 + l16)*PA + kc*32 + quad*8];
    v8s a1 = *(const v8s*)&ldsA[(1*16 + l16)*PA + kc*32 + quad*8];
    #pragma unroll
    for (int g = 0; g < 4; g++){
      acc[0][g] = __builtin_amdgcn_mfma_f32_16x16x32_bf16(a0, bc[g], acc[0][g], 0,0,0);
      acc[1][g] = __builtin_amdgcn_mfma_f32_16x16x32_bf16(a1, bc[g], acc[1][g], 0,0,0);
    }
    #pragma unroll
    for (int g = 0; g < 4; g++) bc[g] = bn[g];
  }

  // ---- epilogue 0: LSTM update + LAYER-0 decision partials -> ldsR[0] ------
  {
    // weight columns 0/1 of the c0n,h0n blocks of W_raise / W_branch
    float2 wrA = *(const float2*)&Wr[(      ch)*2];
    float2 wrB = *(const float2*)&Wr[(128 + ch)*2];
    float2 wbA = *(const float2*)&Wb[(      ch)*2];
    float2 wbB = *(const float2*)&Wb[(128 + ch)*2];
    #pragma unroll
    for (int rt = 0; rt < 2; rt++){
      #pragma unroll
      for (int r = 0; r < 4; r++){
        int k = rt*4 + r;
        int lrow = rt*16 + quad*4 + r;
        int grow = rowbase + lrow;
        int node = grow & 2047;                      // node index within batch
        bool special = (node == e_row) || (node == r_row);
        float iv = acc[rt][0][r] + bias[0];
        float fv = acc[rt][1][r] + bias[1];
        float gv = acc[rt][2][r] + bias[2];
        float ov = acc[rt][3][r] + bias[3];
        float cn = fsigm(fv)*cpre[k] + fsigm(iv)*ftanh(gv);
        float hn = fsigm(ov)*ftanh(cn);
        if (!special){
          c0[(size_t)grow*128 + ch] = cn;
          h0[(size_t)grow*128 + ch] = hn;
        }
        ldsG[lrow*PH + ch] = f2b(hn);   // layer-1 A operand (UNMASKED h0n, per ref)
        // layer-0 decision partial over this thread's channel
        float p0 = cn*wrA.x + hn*wrB.x;
        float p1 = cn*wrA.y + hn*wrB.y;
        float p2 = cn*wbA.x + hn*wbB.x;
        float p3 = cn*wbA.y + hn*wbB.y;
        #pragma unroll
        for (int off = 1; off < 16; off <<= 1){
          p0 += __shfl_xor(p0, off, 64);
          p1 += __shfl_xor(p1, off, 64);
          p2 += __shfl_xor(p2, off, 64);
          p3 += __shfl_xor(p3, off, 64);
        }
        if (l16 == 0){
          float4 pv = {p0, p1, p2, p3};
          *(float4*)&ldsR[0][(lrow*8 + wid)*4] = pv;
        }
      }
    }
  }

  // ---- prefetch c1 rows + layer-1 bias + first B1 frags (pre-barrier) ----
  #pragma unroll
  for (int rt = 0; rt < 2; rt++)
    #pragma unroll
    for (int r = 0; r < 4; r++)
      cpre[rt*4+r] = c1[((size_t)rowbase + rt*16 + quad*4 + r)*128 + ch];
  #pragma unroll
  for (int g = 0; g < 4; g++) bias[g] = b1[g*128 + ch];
  const v8s* Bv1 = (const v8s*)Bsw1;
  #pragma unroll
  for (int g = 0; g < 4; g++) bc[g] = Bv1[(size_t)(g*8 + wid)*64 + lane];

  __syncthreads();   // h0_new + h1_old LDS tiles complete

  // ================= layer 1: gates = [h0_new | h1_old] @ B1 =================
  #pragma unroll
  for (int rt = 0; rt < 2; rt++)
    #pragma unroll
    for (int g = 0; g < 4; g++)
      acc[rt][g] = (v4f){0.f, 0.f, 0.f, 0.f};
  #pragma unroll
  for (int kc = 0; kc < 8; kc++){
    if (kc < 7){
      #pragma unroll
      for (int g = 0; g < 4; g++) bn[g] = Bv1[(size_t)((kc+1)*32 + g*8 + wid)*64 + lane];
    }
    v8s a0, a1;
    if (kc < 4){
      a0 = *(const v8s*)&ldsG[(0*16 + l16)*PH + kc*32 + quad*8];
      a1 = *(const v8s*)&ldsG[(1*16 + l16)*PH + kc*32 + quad*8];
    } else {
      a0 = *(const v8s*)&ldsH[(0*16 + l16)*PH + (kc-4)*32 + quad*8];
      a1 = *(const v8s*)&ldsH[(1*16 + l16)*PH + (kc-4)*32 + quad*8];
    }
    #pragma unroll
    for (int g = 0; g < 4; g++){
      acc[0][g] = __builtin_amdgcn_mfma_f32_16x16x32_bf16(a0, bc[g], acc[0][g], 0,0,0);
      acc[1][g] = __builtin_amdgcn_mfma_f32_16x16x32_bf16(a1, bc[g], acc[1][g], 0,0,0);
    }
    #pragma unroll
    for (int g = 0; g < 4; g++) bc[g] = bn[g];
  }

  // ---- epilogue 1: LSTM update + LAYER-1 decision partials -> ldsR[1] ------
  {
    float2 wrC = *(const float2*)&Wr[(256 + ch)*2];
    float2 wrD = *(const float2*)&Wr[(384 + ch)*2];
    float2 wbC = *(const float2*)&Wb[(256 + ch)*2];
    float2 wbD = *(const float2*)&Wb[(384 + ch)*2];
    #pragma unroll
    for (int rt = 0; rt < 2; rt++){
      #pragma unroll
      for (int r = 0; r < 4; r++){
        int k = rt*4 + r;
        int lrow = rt*16 + quad*4 + r;
        int grow = rowbase + lrow;
        int node = grow & 2047;
        bool special = (node == e_row) || (node == r_row);
        float iv = acc[rt][0][r] + bias[0];
        float fv = acc[rt][1][r] + bias[1];
        float gv = acc[rt][2][r] + bias[2];
        float ov = acc[rt][3][r] + bias[3];
        float cn = fsigm(fv)*cpre[k] + fsigm(iv)*ftanh(gv);
        float hn = fsigm(ov)*ftanh(cn);
        if (!special){
          c1[(size_t)grow*128 + ch] = cn;
          h1[(size_t)grow*128 + ch] = hn;
        }
        float p0 = cn*wrC.x + hn*wrD.x;
        float p1 = cn*wrC.y + hn*wrD.y;
        float p2 = cn*wbC.x + hn*wbD.x;
        float p3 = cn*wbC.y + hn*wbD.y;
        #pragma unroll
        for (int off = 1; off < 16; off <<= 1){
          p0 += __shfl_xor(p0, off, 64);
          p1 += __shfl_xor(p1, off, 64);
          p2 += __shfl_xor(p2, off, 64);
          p3 += __shfl_xor(p3, off, 64);
        }
        if (l16 == 0){
          float4 pv = {p0, p1, p2, p3};
          *(float4*)&ldsR[1][(lrow*8 + wid)*4] = pv;
        }
      }
    }
  }
  __syncthreads();

  // ---- finisher: 32 threads, one row each: cross-wave+cross-slot sum -------
  if (tid < 32){
    int grow = rowbase + tid;
    float s0=0.f, s1=0.f, s2=0.f, s3=0.f;
    #pragma unroll
    for (int w = 0; w < 8; w++){
      float4 pa = *(const float4*)&ldsR[0][(tid*8 + w)*4];
      float4 pb = *(const float4*)&ldsR[1][(tid*8 + w)*4];
      s0 += pa.x + pb.x; s1 += pa.y + pb.y;
      s2 += pa.z + pb.z; s3 += pa.w + pb.w;
    }
    float r0 = s0 + br[0], r1 = s1 + br[1];
    float q0 = s2 + bb[0], q1 = s3 + bb[1];
    float m = fmaxf(r0, r1);
    float e0 = __expf(r0 - m), e1 = __expf(r1 - m);
    float pr = e0 / (e0 + e1), pn = e1 / (e0 + e1);
    float m2 = fmaxf(q0, q1);
    float f0 = __expf(q0 - m2), f1 = __expf(q1 - m2);
    float pt = f0 / (f0 + f1), pf = f1 / (f0 + f1);
    float ipv = ip[grow];
    wbuf[0*BN + grow] = pr * ipv;
    wbuf[1*BN + grow] = pn * pt * ipv;
    wbuf[2*BN + grow] = pn * pf * ipv;
    // CSR edge counting (old kcount)
    atomicAdd(&counts[(b<<11) + ri[grow]], 1);
    atomicAdd(&counts[(b<<11) + ti[grow]], 1);
    atomicAdd(&counts[(b<<11) + fi[grow]], 1);
  }
}

// ---------------- patch decisions at exit/raise rows (need OLD states) ------
__global__ __launch_bounds__(64) void kpatch(
    const float* __restrict__ c0, const float* __restrict__ h0,
    const float* __restrict__ c1, const float* __restrict__ h1,
    const float* __restrict__ Wb, const float* __restrict__ bb,
    const float* __restrict__ ip,
    const int* __restrict__ exit_idx, const int* __restrict__ raise_idx,
    float* __restrict__ wbuf)
{
  int b = blockIdx.x;
  int idx = blockIdx.y ? raise_idx[b] : exit_idx[b];
  int gid = (b << 11) + idx;
  int lane = threadIdx.x;
  const float* bufs[4] = {c0, h0, c1, h1};
  const float* hb = bufs[lane >> 4] + (size_t)gid*128 + (lane & 15)*8;
  float4 hv0 = *(const float4*)hb;
  float4 hv1 = *(const float4*)(hb + 4);
  float hv[8] = {hv0.x, hv0.y, hv0.z, hv0.w, hv1.x, hv1.y, hv1.z, hv1.w};
  const float* wbp = Wb + lane*16;
  float q0=0.f, q1=0.f;
  #pragma unroll
  for (int j = 0; j < 8; j++){
    q0 += hv[j] * wbp[j*2];
    q1 += hv[j] * wbp[j*2+1];
  }
  #pragma unroll
  for (int off = 32; off > 0; off >>= 1){
    q0 += __shfl_xor(q0, off, 64);
    q1 += __shfl_xor(q1, off, 64);
  }
  if (lane == 0){
    q0 += bb[0]; q1 += bb[1];
    float m2 = fmaxf(q0, q1);
    float f0 = __expf(q0 - m2), f1 = __expf(q1 - m2);
    float pt = f0 / (f0 + f1), pf = f1 / (f0 + f1);
    float ipv = ip[gid];
    wbuf[0*BN + gid] = 0.f;          // raise_dec overridden to (0,1)
    wbuf[1*BN + gid] = pt * ipv;
    wbuf[2*BN + gid] = pf * ipv;
  }
}

// ---------------- CSR build: scan (also zeroes cursor) / fill ----------------
__global__ __launch_bounds__(256) void kscan(const int* __restrict__ counts,
                                             int* __restrict__ offsets,
                                             int* __restrict__ cursor){
  __shared__ int lds[256];
  int b = blockIdx.x, tid = threadIdx.x;
  const int* c = counts + b*NN;
  int* o = offsets + b*NN;
  int* cu = cursor + b*NN;
  int v[8]; int s = 0;
  #pragma unroll
  for (int i = 0; i < 8; i++){ v[i] = c[tid*8+i]; s += v[i]; cu[tid*8+i] = 0; }
  lds[tid] = s;
  __syncthreads();
  if (tid == 0){
    int run = 0;
    for (int t = 0; t < 256; t++){ int tmp = lds[t]; lds[t] = run; run += tmp; }
  }
  __syncthreads();
  int off = lds[tid];
  #pragma unroll
  for (int i = 0; i < 8; i++){ o[tid*8+i] = off; off += v[i]; }
}

__global__ void kfill(const int* __restrict__ ri, const int* __restrict__ ti,
                      const int* __restrict__ fi, const int* __restrict__ offsets,
                      int* __restrict__ cursor, unsigned short* __restrict__ edges){
  int gid = blockIdx.x*256 + threadIdx.x;
  int b = gid >> 11, n = gid & 2047;
  size_t ebase = (size_t)b*3*NN;
  int t0 = ri[gid]; int p0 = atomicAdd(&cursor[b*NN+t0], 1);
  edges[ebase + offsets[b*NN+t0] + p0] = (unsigned short)(n);
  int t1 = ti[gid]; int p1 = atomicAdd(&cursor[b*NN+t1], 1);
  edges[ebase + offsets[b*NN+t1] + p1] = (unsigned short)(n | (1<<11));
  int t2 = fi[gid]; int p2 = atomicAdd(&cursor[b*NN+t2], 1);
  edges[ebase + offsets[b*NN+t2] + p2] = (unsigned short)(n | (2<<11));
}

// ---------------- gather + normalize + output (all batches) -----------------
__global__ __launch_bounds__(128) void kagg(
    const float* __restrict__ c0, const float* __restrict__ h0,
    const float* __restrict__ c1, const float* __restrict__ h1,
    const float* __restrict__ ip,
    const float* __restrict__ wbuf, const unsigned short* __restrict__ edges,
    const int* __restrict__ counts, const int* __restrict__ offsets,
    const int* __restrict__ step_limits, const int* __restrict__ cur_step,
    float* __restrict__ out)
{
  int gid = blockIdx.x;            // b*N + j
  int b = gid >> 11;
  int tid = threadIdx.x;           // 0..127, channels tid*4..tid*4+3
  size_t obase = (size_t)gid*513;
  const float* bufs[4] = {c0, h0, c1, h1};

  if (cur_step[0] >= step_limits[b]){       // done: copy old state + old ip
    int c = tid*4;
    const float* s = bufs[c >> 7];
    size_t rb = (size_t)gid*128 + (c & 127);
    out[obase + c+0] = s[rb+0];
    out[obase + c+1] = s[rb+1];
    out[obase + c+2] = s[rb+2];
    out[obase + c+3] = s[rb+3];
    if (tid == 0) out[obase + 512] = ip[gid];
    return;
  }

  int cnt = counts[gid], off = offsets[gid];
  const unsigned short* eb = edges + (size_t)b*3*NN + off;
  const float* sb = bufs[tid >> 5];
  int coff = (tid & 31)*4;
  float a0=0.f, a1=0.f, a2=0.f, a3=0.f, ipn=0.f;
  int pk = (cnt > 0) ? eb[0] : 0;
  for (int e = 0; e < cnt; e++){
    int pkn = (e+1 < cnt) ? eb[e+1] : 0;     // prefetch next edge
    int n = pk & 2047, et = pk >> 11;
    float w = wbuf[et*BN + (b<<11) + n];
    float4 sv = *(const float4*)(sb + ((size_t)(b<<11) + n)*128 + coff);
    ipn += w;
    a0 += w * sv.x;
    a1 += w * sv.y;
    a2 += w * sv.z;
    a3 += w * sv.w;
    pk = pkn;
  }
  int c = tid*4;
  float inv = 1.0f / (ipn + 1e-7f);
  out[obase + c+0] = a0*inv;
  out[obase + c+1] = a1*inv;
  out[obase + c+2] = a2*inv;
  out[obase + c+3] = a3*inv;
  if (tid == 0) out[obase + 512] = ipn;
}

extern "C" void kernel_launch(void* const* d_in, const int* in_sizes, int n_in,
                              void* d_out, int out_size, void* d_ws, size_t ws_size,
                              hipStream_t stream){
  const float* ne  = (const float*)d_in[0];
  float* c0  = (float*)d_in[1];   // updated in place (harness restores before every launch)
  float* h0  = (float*)d_in[2];
  float* c1  = (float*)d_in[3];
  float* h1  = (float*)d_in[4];
  const float* ip  = (const float*)d_in[5];
  const float* Wi0 = (const float*)d_in[6];
  const float* Wh0 = (const float*)d_in[7];
  const float* b0  = (const float*)d_in[8];
  const float* Wi1 = (const float*)d_in[9];
  const float* Wh1 = (const float*)d_in[10];
  const float* b1  = (const float*)d_in[11];
  const float* Wr  = (const float*)d_in[12];
  const float* br  = (const float*)d_in[13];
  const float* Wb  = (const float*)d_in[14];
  const float* bb  = (const float*)d_in[15];
  const int* ti  = (const int*)d_in[16];
  const int* fi  = (const int*)d_in[17];
  const int* ri  = (const int*)d_in[18];
  const int* ei  = (const int*)d_in[19];
  const int* rni = (const int*)d_in[20];
  const int* sl  = (const int*)d_in[21];
  const int* cs  = (const int*)d_in[22];
  float* out = (float*)d_out;

  // --- ws layout ---
  uint8_t* ws = (uint8_t*)d_ws;
  unsigned short* Bsw0    = (unsigned short*)(ws + 0);         // 262144 B
  unsigned short* Bsw1    = (unsigned short*)(ws + 262144);    // 262144 B
  float*          wbuf    = (float*)(ws + 655360);             // 786432 B
  int*            counts  = (int*)(ws + 1441792);              // 262144 B
  int*            offsets = (int*)(ws + 1703936);              // 262144 B
  int*            cursor  = (int*)(ws + 1966080);              // 262144 B
  unsigned short* edges   = (unsigned short*)(ws + 2228224);   // 393216 B

  hipMemsetAsync(counts, 0, BN*sizeof(int), stream);

  kswz<<<512, 64, 0, stream>>>(Wi0, Wh0, Wi1, Wh1, Bsw0, Bsw1);

  // fused 2-layer LSTM + decision head; skips done batches; skips writes at
  // exit/raise rows (keeps old state there; replaces ksave/krestore)
  klstm2<<<BN/ROWSB, 512, 0, stream>>>(ne, c0, h0, c1, h1, Bsw0, b0, Bsw1, b1,
                                       Wr, br, Wb, bb, ip, ei, rni,
                                       ri, ti, fi, counts, wbuf, sl, cs);

  // fix decisions at exit/raise rows (branch softmax needs OLD states there)
  kpatch<<<dim3(BB, 2), 64, 0, stream>>>(c0, h0, c1, h1, Wb, bb, ip, ei, rni, wbuf);

  kscan<<<BB, 256, 0, stream>>>(counts, offsets, cursor);
  kfill<<<BN/256, 256, 0, stream>>>(ri, ti, fi, offsets, cursor, edges);

  kagg<<<BN, 128, 0, stream>>>(c0, h0, c1, h1, ip, wbuf, edges, counts, offsets,
                               sl, cs, out);
}